// Round 5
// baseline (10258.510 us; speedup 1.0000x reference)
//
#include <hip/hip_runtime.h>

// FPS: x (B=64, N=65536, 3) f32 -> out (B, M=2048, 3) f32 gathered points.
// Verified fp semantics (round 3, absmax=0):
//   d = fma(dz,dz, round(dx*dx) + round(dy*dy)), min via fminf,
//   argmax tie-break = smallest global index.
// Round-5: xyz shipped in seq-stamped messages (no dependent coord fetch),
// parallel wave0 butterfly block-combine (1 barrier/iter), all-thread
// polling (no broadcast barrier), XCD-affine block swizzle.

#define FPS_B 64
#define FPS_N 65536
#define FPS_M 2048
#define FPS_T 1024
#define FPS_Q 4                    // blocks per batch
#define FPS_GT (FPS_T * FPS_Q)     // 4096 threads per batch
#define FPS_PPT (FPS_N / FPS_GT)   // 16 points per thread
#define FPS_WAVES (FPS_T / 64)     // 16 waves per block

// workspace: per batch, 4 blocks x 2 ring slots, 64B each (4 u64 used)
#define SLOT_U64 8
#define BATCH_U64 (FPS_Q * 2 * SLOT_U64)   // 64 u64 = 512B per batch

#define AG_LOAD(p)     __hip_atomic_load((p), __ATOMIC_RELAXED, __HIP_MEMORY_SCOPE_AGENT)
#define AG_STORE(p, v) __hip_atomic_store((p), (v), __ATOMIC_RELAXED, __HIP_MEMORY_SCOPE_AGENT)

__global__ __launch_bounds__(FPS_T, 4)
void fps_kernel(const float* __restrict__ x, float* __restrict__ out,
                unsigned long long* __restrict__ cand) {
    const int bid = blockIdx.x;
    // XCD-affine swizzle: batch b's 4 blocks all have bid % 8 == b % 8
    // (same XCD under round-robin dispatch). Bijective over [0,256).
    const int c = bid & 7;
    const int v = bid >> 3;        // 0..31
    const int u = v >> 2;          // 0..7
    const int q = v & 3;           // block-in-batch
    const int b = u * 8 + c;       // batch

    const float* xb = x + (size_t)b * FPS_N * 3;
    float* ob = out + (size_t)b * FPS_M * 3;
    unsigned long long* cb = cand + (size_t)b * BATCH_U64;

    __shared__ float s_val[FPS_WAVES];
    __shared__ int   s_idx[FPS_WAVES];
    __shared__ float s_x[FPS_WAVES], s_y[FPS_WAVES], s_z[FPS_WAVES];

    const int t = threadIdx.x;
    const int wave = t >> 6;
    const int lane = t & 63;
    const int g = q * FPS_T + t;   // 0..4095 within batch

    // one-time coordinate load; point i = k*4096 + g
    float cx[FPS_PPT], cy[FPS_PPT], cz[FPS_PPT], mind[FPS_PPT];
#pragma unroll
    for (int k = 0; k < FPS_PPT; ++k) {
        const int i = k * FPS_GT + g;
        cx[k] = xb[3 * i + 0];
        cy[k] = xb[3 * i + 1];
        cz[k] = xb[3 * i + 2];
        mind[k] = INFINITY;
    }

    float px = xb[0], py = xb[1], pz = xb[2];
    if (q == 0 && t == 0) { ob[0] = px; ob[1] = py; ob[2] = pz; }

    long long poll_budget = 1LL << 20;   // fail-safe: degrade, don't hang

    for (int s = 1; s < FPS_M; ++s) {
        float best = -INFINITY;
        int besti = 0;
        float bx = 0.f, by = 0.f, bz = 0.f;
#pragma unroll
        for (int k = 0; k < FPS_PPT; ++k) {
            const float dx = __fsub_rn(cx[k], px);
            const float dy = __fsub_rn(cy[k], py);
            const float dz = __fsub_rn(cz[k], pz);
            const float sxy = __fadd_rn(__fmul_rn(dx, dx), __fmul_rn(dy, dy));
            const float d = __builtin_fmaf(dz, dz, sxy);
            const float md = fminf(mind[k], d);
            mind[k] = md;
            if (md > best) {
                best = md; besti = k * FPS_GT + g;
                bx = cx[k]; by = cy[k]; bz = cz[k];
            }
        }

        // wave argmax (64 lanes) carrying coords, smallest-index tie-break
#pragma unroll
        for (int m = 32; m >= 1; m >>= 1) {
            const float ov = __shfl_xor(best, m);
            const int   oi = __shfl_xor(besti, m);
            const float ox = __shfl_xor(bx, m);
            const float oy = __shfl_xor(by, m);
            const float oz = __shfl_xor(bz, m);
            if (ov > best || (ov == best && oi < besti)) {
                best = ov; besti = oi; bx = ox; by = oy; bz = oz;
            }
        }
        if (lane == 0) {
            s_val[wave] = best; s_idx[wave] = besti;
            s_x[wave] = bx; s_y[wave] = by; s_z[wave] = bz;
        }
        __syncthreads();   // the only barrier per iteration

        const int ring = s & 1;
        const unsigned long long want = (unsigned long long)s;

        if (wave == 0) {
            // 64 lanes mirror the 16 wave entries; 4-round butterfly
            const int w16 = lane & 15;
            float bv = s_val[w16];
            int   bi = s_idx[w16];
            float wx = s_x[w16], wy = s_y[w16], wz = s_z[w16];
#pragma unroll
            for (int m = 8; m >= 1; m >>= 1) {
                const float ov = __shfl_xor(bv, m);
                const int   oi = __shfl_xor(bi, m);
                const float ox = __shfl_xor(wx, m);
                const float oy = __shfl_xor(wy, m);
                const float oz = __shfl_xor(wz, m);
                if (ov > bv || (ov == bv && oi < bi)) {
                    bv = ov; bi = oi; wx = ox; wy = oy; wz = oz;
                }
            }
            if (lane == 0) {
                // w0: [63:32]=val bits (val>=0 => monotone u64 max == argmax),
                //     [26:11]=~idx (smaller idx wins ties), [10:0]=seq
                unsigned long long* sp = &cb[(q * 2 + ring) * SLOT_U64];
                const unsigned long long w0 =
                    ((unsigned long long)__float_as_uint(bv) << 32) |
                    ((unsigned long long)((~(unsigned)bi) & 0xFFFFu) << 11) |
                    want;
                AG_STORE(&sp[0], w0);
                AG_STORE(&sp[1], ((unsigned long long)__float_as_uint(wx) << 32) | want);
                AG_STORE(&sp[2], ((unsigned long long)__float_as_uint(wy) << 32) | want);
                AG_STORE(&sp[3], ((unsigned long long)__float_as_uint(wz) << 32) | want);
            }
        }

        // all threads poll w0 of all 4 slots (uniform loads per wave)
        unsigned long long m0 = 0, m1 = 0, m2 = 0, m3 = 0;
        unsigned mask = 0xFu;
        while (mask && poll_budget > 0) {
            if (mask & 1u) {
                const unsigned long long vv = AG_LOAD(&cb[(0 * 2 + ring) * SLOT_U64]);
                if ((vv & 0x7FFull) == want) { m0 = vv; mask &= ~1u; }
            }
            if (mask & 2u) {
                const unsigned long long vv = AG_LOAD(&cb[(1 * 2 + ring) * SLOT_U64]);
                if ((vv & 0x7FFull) == want) { m1 = vv; mask &= ~2u; }
            }
            if (mask & 4u) {
                const unsigned long long vv = AG_LOAD(&cb[(2 * 2 + ring) * SLOT_U64]);
                if ((vv & 0x7FFull) == want) { m2 = vv; mask &= ~4u; }
            }
            if (mask & 8u) {
                const unsigned long long vv = AG_LOAD(&cb[(3 * 2 + ring) * SLOT_U64]);
                if ((vv & 0x7FFull) == want) { m3 = vv; mask &= ~8u; }
            }
            --poll_budget;
        }
        const unsigned long long w01 = m0 > m1 ? m0 : m1;
        const unsigned long long w23 = m2 > m3 ? m2 : m3;
        const unsigned long long w = w01 > w23 ? w01 : w23;
        const int wb = (w == m0) ? 0 : ((w == m1) ? 1 : ((w == m2) ? 2 : 3));

        // fetch winner coords from its (seq-stamped) message words
        const unsigned long long* wp = &cb[(wb * 2 + ring) * SLOT_U64];
        unsigned long long v1, v2, v3;
        do { v1 = AG_LOAD(&wp[1]); } while ((v1 & 0x7FFull) != want && --poll_budget > 0);
        do { v2 = AG_LOAD(&wp[2]); } while ((v2 & 0x7FFull) != want && --poll_budget > 0);
        do { v3 = AG_LOAD(&wp[3]); } while ((v3 & 0x7FFull) != want && --poll_budget > 0);
        px = __uint_as_float((unsigned)(v1 >> 32));
        py = __uint_as_float((unsigned)(v2 >> 32));
        pz = __uint_as_float((unsigned)(v3 >> 32));

        if (q == 0 && t == 0) {
            ob[3 * s + 0] = px; ob[3 * s + 1] = py; ob[3 * s + 2] = pz;
        }
    }
}

extern "C" void kernel_launch(void* const* d_in, const int* in_sizes, int n_in,
                              void* d_out, int out_size, void* d_ws, size_t ws_size,
                              hipStream_t stream) {
    const float* x = (const float*)d_in[0];
    float* out = (float*)d_out;
    unsigned long long* cand = (unsigned long long*)d_ws;
    (void)in_sizes; (void)n_in; (void)out_size; (void)ws_size;
    // zero sync workspace each launch: stale seq can never match (seq >= 1)
    hipMemsetAsync(d_ws, 0, FPS_B * BATCH_U64 * sizeof(unsigned long long), stream);
    fps_kernel<<<FPS_B * FPS_Q, FPS_T, 0, stream>>>(x, out, cand);
}

// Round 6
// 7844.035 us; speedup vs baseline: 1.3078x; 1.3078x over previous
//
#include <hip/hip_runtime.h>

// FPS: x (B=64, N=65536, 3) f32 -> out (B, M=2048, 3) f32 gathered points.
// Verified fp semantics (round 3, absmax=0):
//   d = fma(dz,dz, round(dx*dx) + round(dy*dy)), min via fminf,
//   argmax tie-break = smallest global index.
// Round-6:
//  - asm "+v" loop-carried pins force coord register residency (r4/r5 had
//    VGPR_Count 48/64 < 64 floats => compiler was re-loading coords from
//    cache every iteration; that was the 4.6us/iter floor)
//  - barrier-free iteration: seq-stamped LDS entries/broadcast, only wave 0
//    polls the global slots (lanes 0-3, 1 instruction per round)
//  - depth-2 global ring + stamps unchanged (proven r4/r5)

#define FPS_B 64
#define FPS_N 65536
#define FPS_M 2048
#define FPS_T 1024
#define FPS_Q 4                    // blocks per batch
#define FPS_GT (FPS_T * FPS_Q)     // 4096 threads per batch
#define FPS_PPT (FPS_N / FPS_GT)   // 16 points per thread
#define FPS_WAVES (FPS_T / 64)     // 16 waves per block

#define SLOT_U64 8                 // 64B global slot
#define BATCH_U64 (FPS_Q * 2 * SLOT_U64)

#define AG_LOAD(p)    __hip_atomic_load((p), __ATOMIC_RELAXED, __HIP_MEMORY_SCOPE_AGENT)
#define AG_STORE(p,v) __hip_atomic_store((p), (v), __ATOMIC_RELAXED, __HIP_MEMORY_SCOPE_AGENT)
#define WG_LOAD(p)    __hip_atomic_load((p), __ATOMIC_RELAXED, __HIP_MEMORY_SCOPE_WORKGROUP)
#define WG_STORE(p,v) __hip_atomic_store((p), (v), __ATOMIC_RELAXED, __HIP_MEMORY_SCOPE_WORKGROUP)

#define PIN4(a,b,c,d) asm volatile("" : "+v"(a), "+v"(b), "+v"(c), "+v"(d))

__global__ __launch_bounds__(FPS_T, 4)
void fps_kernel(const float* __restrict__ x, float* __restrict__ out,
                unsigned long long* __restrict__ cand) {
    const int bid = blockIdx.x;
    // XCD-affine swizzle: batch b's 4 blocks share bid%8 (same XCD under
    // round-robin dispatch). Bijective over [0,256).
    const int c = bid & 7;
    const int v = bid >> 3;
    const int q = v & 3;           // block-in-batch
    const int b = (v >> 2) * 8 + c;

    const float* xb = x + (size_t)b * FPS_N * 3;
    float* ob = out + (size_t)b * FPS_M * 3;
    unsigned long long* cb = cand + (size_t)b * BATCH_U64;

    // stamped LDS mailboxes: 16 wave entries x 4 words, 3 broadcast words
    __shared__ unsigned long long s_entry[FPS_WAVES * 4];
    __shared__ unsigned long long s_bcast[3];

    const int t = threadIdx.x;
    const int wave = t >> 6;
    const int lane = t & 63;
    const int g = q * FPS_T + t;   // 0..4095 within batch

    if (t < FPS_WAVES * 4) WG_STORE(&s_entry[t], 0ull);
    if (t >= 64 && t < 67)  WG_STORE(&s_bcast[t - 64], 0ull);
    __syncthreads();               // the only barrier in the kernel

    // one-time coordinate load; point i = k*4096 + g (ascending in k)
    float cx0,cx1,cx2,cx3,cx4,cx5,cx6,cx7,cx8,cx9,cx10,cx11,cx12,cx13,cx14,cx15;
    float cy0,cy1,cy2,cy3,cy4,cy5,cy6,cy7,cy8,cy9,cy10,cy11,cy12,cy13,cy14,cy15;
    float cz0,cz1,cz2,cz3,cz4,cz5,cz6,cz7,cz8,cz9,cz10,cz11,cz12,cz13,cz14,cz15;
    float mind[FPS_PPT];
#define LOADK(k) do { const int i = (k) * FPS_GT + g; \
        cx##k = xb[3*i+0]; cy##k = xb[3*i+1]; cz##k = xb[3*i+2]; \
        mind[k] = INFINITY; } while (0)
    LOADK(0); LOADK(1); LOADK(2); LOADK(3); LOADK(4); LOADK(5); LOADK(6); LOADK(7);
    LOADK(8); LOADK(9); LOADK(10); LOADK(11); LOADK(12); LOADK(13); LOADK(14); LOADK(15);
#undef LOADK

    float px = xb[0], py = xb[1], pz = xb[2];
    if (q == 0 && t == 0) { ob[0] = px; ob[1] = py; ob[2] = pz; }

    long long budget = 1LL << 22;  // fail-safe: degrade, don't hang

    for (int s = 1; s < FPS_M; ++s) {
        // force the 48 coord values to stay in VGPRs across iterations
        PIN4(cx0,cx1,cx2,cx3);   PIN4(cx4,cx5,cx6,cx7);
        PIN4(cx8,cx9,cx10,cx11); PIN4(cx12,cx13,cx14,cx15);
        PIN4(cy0,cy1,cy2,cy3);   PIN4(cy4,cy5,cy6,cy7);
        PIN4(cy8,cy9,cy10,cy11); PIN4(cy12,cy13,cy14,cy15);
        PIN4(cz0,cz1,cz2,cz3);   PIN4(cz4,cz5,cz6,cz7);
        PIN4(cz8,cz9,cz10,cz11); PIN4(cz12,cz13,cz14,cz15);

        float best = -INFINITY;
        int besti = 0;
        float bx = 0.f, by = 0.f, bz = 0.f;
#define STEPK(k) do { \
        const float dx = __fsub_rn(cx##k, px); \
        const float dy = __fsub_rn(cy##k, py); \
        const float dz = __fsub_rn(cz##k, pz); \
        const float sxy = __fadd_rn(__fmul_rn(dx, dx), __fmul_rn(dy, dy)); \
        const float d = __builtin_fmaf(dz, dz, sxy); \
        const float md = fminf(mind[k], d); \
        mind[k] = md; \
        if (md > best) { best = md; besti = (k) * FPS_GT + g; \
                         bx = cx##k; by = cy##k; bz = cz##k; } } while (0)
        STEPK(0); STEPK(1); STEPK(2); STEPK(3); STEPK(4); STEPK(5); STEPK(6); STEPK(7);
        STEPK(8); STEPK(9); STEPK(10); STEPK(11); STEPK(12); STEPK(13); STEPK(14); STEPK(15);
#undef STEPK

        // wave argmax on (val, idx), smallest-index tie-break
#pragma unroll
        for (int m = 32; m >= 1; m >>= 1) {
            const float ov = __shfl_xor(best, m);
            const int   oi = __shfl_xor(besti, m);
            if (ov > best || (ov == best && oi < besti)) { best = ov; besti = oi; }
        }
        // winner lane = besti & 63 (i = k*4096 + q*1024 + t; 4096,1024 ≡ 0 mod 64)
        const int wl = besti & 63;
        const float wx = __shfl(bx, wl);
        const float wy = __shfl(by, wl);
        const float wz = __shfl(bz, wl);

        const unsigned long long want = (unsigned long long)s;
        const int ring = s & 1;

        // wave leaders publish stamped entry (lanes 0-3, one store instr)
        if (lane < 4) {
            unsigned long long w;
            if (lane == 0)
                w = ((unsigned long long)__float_as_uint(best) << 32) |
                    ((unsigned long long)((~(unsigned)besti) & 0xFFFFu) << 11) | want;
            else if (lane == 1) w = ((unsigned long long)__float_as_uint(wx) << 32) | want;
            else if (lane == 2) w = ((unsigned long long)__float_as_uint(wy) << 32) | want;
            else                w = ((unsigned long long)__float_as_uint(wz) << 32) | want;
            WG_STORE(&s_entry[wave * 4 + lane], w);
        }

        if (wave == 0) {
            // gather 16 entries (lanes mirror mod 16), stamped spin
            const int e = lane & 15;
            unsigned long long e0;
            do { e0 = WG_LOAD(&s_entry[e * 4]); } while ((e0 & 0x7FFull) != want && --budget > 0);
            // butterfly within 16-lane groups
#pragma unroll
            for (int m = 8; m >= 1; m >>= 1) {
                const unsigned long long o = __shfl_xor(e0, m);
                if (o > e0) e0 = o;
            }
            // winner wave in this block: idx&1023 = t, wave = t>>6
            const int widx = (int)((~(unsigned)(e0 >> 11)) & 0xFFFFu);
            const int wv = (widx & 1023) >> 6;
            unsigned long long cw = 0;
            if (lane >= 1 && lane <= 3) {
                do { cw = WG_LOAD(&s_entry[wv * 4 + lane]); } while ((cw & 0x7FFull) != want && --budget > 0);
            }
            // publish block winner to global slot (lanes 0-3, one store instr)
            if (lane < 4) {
                const unsigned long long pw = (lane == 0) ? e0 : cw;
                AG_STORE(&cb[(q * 2 + ring) * SLOT_U64 + lane], pw);
            }
            // poll all 4 slots' w0 (lane l <-> slot l), stamped spin
            unsigned long long pv = 0;
            if (lane < 4) {
                do { pv = AG_LOAD(&cb[(lane * 2 + ring) * SLOT_U64]); } while ((pv & 0x7FFull) != want && --budget > 0);
            }
            // combine across lanes 0-3
            {
                const unsigned long long o1 = __shfl_xor(pv, 1);
                if (o1 > pv) pv = o1;
                const unsigned long long o2 = __shfl_xor(pv, 2);
                if (o2 > pv) pv = o2;
            }
            // winner block from idx: g = idx&4095, q_win = g>>10
            const int widx2 = (int)((~(unsigned)(pv >> 11)) & 0xFFFFu);
            const int wb = (widx2 & 4095) >> 10;
            unsigned long long cw2 = 0;
            if (lane >= 1 && lane <= 3) {
                do { cw2 = AG_LOAD(&cb[(wb * 2 + ring) * SLOT_U64 + lane]); } while ((cw2 & 0x7FFull) != want && --budget > 0);
                WG_STORE(&s_bcast[lane - 1], cw2);
            }
        }

        // all waves: stamped spin on broadcast coords
        unsigned long long b0, b1, b2;
        do { b0 = WG_LOAD(&s_bcast[0]); } while ((b0 & 0x7FFull) != want && --budget > 0);
        do { b1 = WG_LOAD(&s_bcast[1]); } while ((b1 & 0x7FFull) != want && --budget > 0);
        do { b2 = WG_LOAD(&s_bcast[2]); } while ((b2 & 0x7FFull) != want && --budget > 0);
        px = __uint_as_float((unsigned)(b0 >> 32));
        py = __uint_as_float((unsigned)(b1 >> 32));
        pz = __uint_as_float((unsigned)(b2 >> 32));

        if (q == 0 && t == 0) {
            ob[3 * s + 0] = px; ob[3 * s + 1] = py; ob[3 * s + 2] = pz;
        }
    }
}

extern "C" void kernel_launch(void* const* d_in, const int* in_sizes, int n_in,
                              void* d_out, int out_size, void* d_ws, size_t ws_size,
                              hipStream_t stream) {
    const float* x = (const float*)d_in[0];
    float* out = (float*)d_out;
    unsigned long long* cand = (unsigned long long*)d_ws;
    (void)in_sizes; (void)n_in; (void)out_size; (void)ws_size;
    // zero sync workspace each launch (stale stamps can't match: seq >= 1,
    // and identical-seq stale data from a prior replay is prevented too)
    hipMemsetAsync(d_ws, 0, FPS_B * BATCH_U64 * sizeof(unsigned long long), stream);
    fps_kernel<<<FPS_B * FPS_Q, FPS_T, 0, stream>>>(x, out, cand);
}